// Round 4
// baseline (336.202 us; speedup 1.0000x reference)
//
#include <hip/hip_runtime.h>

// Problem constants
#define S_DIM 8192
#define K_DIM 1024
#define RO_DIM 4096
#define O_DIM 64
#define SO (S_DIM * O_DIM)

typedef __attribute__((ext_vector_type(8))) __bf16 bf16x8;
typedef __attribute__((ext_vector_type(16))) float floatx16;
typedef __attribute__((ext_vector_type(4))) unsigned short ushx4;

__device__ inline unsigned short f2bf(float f) {
  unsigned u = __builtin_bit_cast(unsigned, f);
  u += 0x7fff + ((u >> 16) & 1);  // round-to-nearest-even
  return (unsigned short)(u >> 16);
}
__device__ inline float bf2f(unsigned short h) {
  unsigned u = ((unsigned)h) << 16;
  return __builtin_bit_cast(float, u);
}

// ---------------------------------------------------------------- cast X,W -> bf16
__global__ __launch_bounds__(256) void cast_kernel(const float* __restrict__ X,
                                                   const float* __restrict__ W,
                                                   unsigned short* __restrict__ Xb,
                                                   unsigned short* __restrict__ Wb) {
  int i = blockIdx.x * 256 + threadIdx.x;
  const int NX4 = (S_DIM * K_DIM) / 4;
  float4 v;
  unsigned short* dst;
  if (i < NX4) {
    v = ((const float4*)X)[i];
    dst = Xb + (size_t)i * 4;
  } else {
    int j = i - NX4;
    v = ((const float4*)W)[j];
    dst = Wb + (size_t)j * 4;
  }
  ushx4 o;
  o.x = f2bf(v.x); o.y = f2bf(v.y); o.z = f2bf(v.z); o.w = f2bf(v.w);
  *(ushx4*)dst = o;
}

// ---------------------------------------------------------------- fused GEMM+sigmoid+rule-reduce
// 128x128 tile, BK=32, 4 waves x (2x2) 32x32x16 MFMA fragments.
// - 32x32x16 halves MFMA inst count vs 16x16x32 (R3: MfmaUtil 22.6%, epilogue
//   + issue overhead bound); ceiling 2382 vs 2075 TF.
// - Bias folded into acc init (MFMA C=b exactly reproduces XW^T+b).
// - Epilogue de-serialized: zero ypart, then BOTH wn groups ds_add_f32
//   concurrently (R3 had wn0-write/barrier/wn1-add: ~2x epilogue on the
//   critical path). Lambda staged in a 1KB LDS side-buffer at kernel start.
// - K-chunk XOR swizzle ((row>>1)&3) at the GLOBAL address of global_load_lds
//   (LDS dest stays wave-uniform+lane*16); read applies the same XOR.
//   R2/R3: conflicts 10M -> 1.6M.
// - LDS: tiles (16KB) UNIONed with epilogue ypart (32KB) + 1KB lambda = 33KB.
// - NO min-waves bound: forcing 5 waves/EU spilled the accumulators
//   (R2: VGPR 92->48, WRITE_SIZE 65->417MB, 302us).
__global__ __launch_bounds__(256) void gemm_kernel(const unsigned short* __restrict__ Xb,
                                                   const unsigned short* __restrict__ Wb,
                                                   const float* __restrict__ bias,
                                                   const float* __restrict__ lam,
                                                   unsigned short* __restrict__ partial) {
  __shared__ __align__(16) unsigned char smem[33792];
  unsigned short* Atile = (unsigned short*)smem;          // 128 rows x 32 k (8 KB)
  unsigned short* Btile = (unsigned short*)(smem + 8192); // 8 KB
  float* ypart = (float*)smem;                            // 128 x 64 fp32 (32 KB, epilogue, unioned)
  float* lamsh = (float*)(smem + 32768);                  // [2][128] (1 KB, NOT unioned)

  const int t = threadIdx.x;
  const int lane = t & 63;
  const int w = t >> 6;
  const int wm = w & 1;        // wave row half (rows wm*64..+63)
  const int wn = w >> 1;       // wave col half (cols wn*64..+63) == rule within tile
  const int l32 = lane & 31;
  const int kg = lane >> 5;    // k-group within fragment (0..1)
  const int gm0 = blockIdx.y * 128;
  const int gn0 = blockIdx.x * 128;

  // stage lambda for this block's 2 rules: lamsh[rl*128 + row]
  {
    int rl = t >> 7, row = t & 127;
    lamsh[t] = lam[(size_t)(gm0 + row) * 64 + blockIdx.x * 2 + rl];
  }

  // acc init = bias (C/D col = lane&31; col is the same for all 16 regs and both mi)
  float bv0 = bias[gn0 + wn * 64 + 0 * 32 + l32];
  float bv1 = bias[gn0 + wn * 64 + 1 * 32 + l32];
  floatx16 acc[2][2];
#pragma unroll
  for (int mi = 0; mi < 2; ++mi)
#pragma unroll
    for (int reg = 0; reg < 16; ++reg) {
      acc[mi][0][reg] = bv0;
      acc[mi][1][reg] = bv1;
    }

  for (int k0 = 0; k0 < K_DIM; k0 += 32) {
    __syncthreads();
#pragma unroll
    for (int i = 0; i < 2; ++i) {
      int idx = i * 256 + t;       // 0..511, lane-contiguous within each wave
      int row = idx >> 2;          // tile row 0..127
      int cc = idx & 3;            // LDS chunk slot within BK=32
      int gcc = cc ^ ((row >> 1) & 3);  // global k-chunk held in this slot
      const unsigned short* ga = Xb + (size_t)(gm0 + row) * K_DIM + k0 + gcc * 8;
      const unsigned short* gb = Wb + (size_t)(gn0 + row) * K_DIM + k0 + gcc * 8;
      __builtin_amdgcn_global_load_lds(
          (const __attribute__((address_space(1))) void*)ga,
          (__attribute__((address_space(3))) void*)(Atile + idx * 8), 16, 0, 0);
      __builtin_amdgcn_global_load_lds(
          (const __attribute__((address_space(1))) void*)gb,
          (__attribute__((address_space(3))) void*)(Btile + idx * 8), 16, 0, 0);
    }
    __syncthreads();

    // two k-steps of 16; fragment: A[m=lane&31][k=kg*8+j] -> chunk = s*2+kg
#pragma unroll
    for (int s = 0; s < 2; ++s) {
      bf16x8 af[2], bfr[2];
#pragma unroll
      for (int mi = 0; mi < 2; ++mi) {
        int row = wm * 64 + mi * 32 + l32;
        int cc = (s * 2 + kg) ^ ((row >> 1) & 3);
        af[mi] = *(const bf16x8*)(Atile + row * 32 + cc * 8);
      }
#pragma unroll
      for (int ni = 0; ni < 2; ++ni) {
        int row = wn * 64 + ni * 32 + l32;
        int cc = (s * 2 + kg) ^ ((row >> 1) & 3);
        bfr[ni] = *(const bf16x8*)(Btile + row * 32 + cc * 8);
      }
#pragma unroll
      for (int mi = 0; mi < 2; ++mi)
#pragma unroll
        for (int ni = 0; ni < 2; ++ni)
          acc[mi][ni] = __builtin_amdgcn_mfma_f32_32x32x16_bf16(af[mi], bfr[ni], acc[mi][ni], 0, 0, 0);
    }
  }

  // ---- epilogue (tiles dead; smem reused as ypart) ----
  __syncthreads();
  // zero ypart: 8192 floats by 256 threads, 8 float4 each
#pragma unroll
  for (int j = 0; j < 8; ++j)
    ((float4*)ypart)[j * 256 + t] = (float4){0.f, 0.f, 0.f, 0.f};
  __syncthreads();

  // both wn groups accumulate concurrently (ds_add_f32, 2-way collisions max)
#pragma unroll
  for (int mi = 0; mi < 2; ++mi) {
#pragma unroll
    for (int reg = 0; reg < 16; ++reg) {
      int row = wm * 64 + mi * 32 + (reg & 3) + 8 * (reg >> 2) + 4 * kg;
      float lv = lamsh[wn * 128 + row];
#pragma unroll
      for (int ni = 0; ni < 2; ++ni) {
        float z = acc[mi][ni][reg];
        float h = 1.f / (1.f + __expf(-z));
        atomicAdd(&ypart[row * O_DIM + ni * 32 + l32], lv * h);
      }
    }
  }
  __syncthreads();

  // write 128x64 bf16 slice, coalesced (2048 x 8B by 256 threads)
  unsigned short* pdst = partial + (size_t)blockIdx.x * SO + (size_t)gm0 * O_DIM;
#pragma unroll
  for (int j = 0; j < 8; ++j) {
    int q = j * 256 + t;
    const float* src = ypart + q * 4;
    ushx4 o;
    o.x = f2bf(src[0]); o.y = f2bf(src[1]); o.z = f2bf(src[2]); o.w = f2bf(src[3]);
    ((ushx4*)pdst)[q] = o;
  }
}

// ---------------------------------------------------------------- final reduce over 32 N-tiles
__global__ __launch_bounds__(256) void reduce_kernel(const unsigned short* __restrict__ partial,
                                                     float* __restrict__ Y) {
  int i4 = blockIdx.x * 256 + threadIdx.x;  // index of a 4-elem group
  float s0 = 0.f, s1 = 0.f, s2 = 0.f, s3 = 0.f;
#pragma unroll
  for (int c = 0; c < 32; ++c) {
    ushx4 v = ((const ushx4*)(partial + (size_t)c * SO))[i4];
    s0 += bf2f(v.x); s1 += bf2f(v.y); s2 += bf2f(v.z); s3 += bf2f(v.w);
  }
  ((float4*)Y)[i4] = (float4){s0, s1, s2, s3};
}

extern "C" void kernel_launch(void* const* d_in, const int* in_sizes, int n_in,
                              void* d_out, int out_size, void* d_ws, size_t ws_size,
                              hipStream_t stream) {
  const float* X = (const float*)d_in[0];     // [8192,1024]
  const float* W = (const float*)d_in[1];     // [4096,1024]
  const float* b = (const float*)d_in[2];     // [4096]
  const float* lam = (const float*)d_in[3];   // [8192,64]
  float* Y = (float*)d_out;                   // [8192,64]

  unsigned short* Xb = (unsigned short*)d_ws;                       // 16 MB
  unsigned short* Wb = Xb + (size_t)S_DIM * K_DIM;                  // 8 MB
  unsigned short* partial = Wb + (size_t)RO_DIM * K_DIM;            // 32 slices x 1 MB = 32 MB

  int nCast = ((S_DIM + RO_DIM) * K_DIM / 4) / 256;  // 12288 blocks
  cast_kernel<<<nCast, 256, 0, stream>>>(X, W, Xb, Wb);

  dim3 g(RO_DIM / 128, S_DIM / 128);  // (32, 64)
  gemm_kernel<<<g, 256, 0, stream>>>(Xb, Wb, b, lam, partial);

  reduce_kernel<<<SO / 1024, 256, 0, stream>>>(partial, Y);
}

// Round 5
// 200.221 us; speedup vs baseline: 1.6792x; 1.6792x over previous
//
#include <hip/hip_runtime.h>

// Problem constants
#define S_DIM 8192
#define K_DIM 1024
#define RO_DIM 4096
#define O_DIM 64
#define SO (S_DIM * O_DIM)

typedef __attribute__((ext_vector_type(8))) __bf16 bf16x8;
typedef __attribute__((ext_vector_type(4))) float floatx4;
typedef __attribute__((ext_vector_type(4))) unsigned short ushx4;

__device__ inline unsigned short f2bf(float f) {
  unsigned u = __builtin_bit_cast(unsigned, f);
  u += 0x7fff + ((u >> 16) & 1);  // round-to-nearest-even
  return (unsigned short)(u >> 16);
}
__device__ inline float bf2f(unsigned short h) {
  unsigned u = ((unsigned)h) << 16;
  return __builtin_bit_cast(float, u);
}

// ---------------------------------------------------------------- cast X,W -> bf16
__global__ __launch_bounds__(256) void cast_kernel(const float* __restrict__ X,
                                                   const float* __restrict__ W,
                                                   unsigned short* __restrict__ Xb,
                                                   unsigned short* __restrict__ Wb) {
  int i = blockIdx.x * 256 + threadIdx.x;
  const int NX4 = (S_DIM * K_DIM) / 4;
  float4 v;
  unsigned short* dst;
  if (i < NX4) {
    v = ((const float4*)X)[i];
    dst = Xb + (size_t)i * 4;
  } else {
    int j = i - NX4;
    v = ((const float4*)W)[j];
    dst = Wb + (size_t)j * 4;
  }
  ushx4 o;
  o.x = f2bf(v.x); o.y = f2bf(v.y); o.z = f2bf(v.z); o.w = f2bf(v.w);
  *(ushx4*)dst = o;
}

// ---------------------------------------------------------------- fused GEMM+sigmoid+rule-reduce
// 128x128 tile, BK=32, 16x16x32 MFMA (R4's 32x32 shape regressed: its 32-row
// read pattern is inherently 4-way bank-conflicted -> conflicts 1.6M->8.4M).
// Fragment partition: wave (wm,oh) = rows wm*64..+63 x cols {oh*32..+31} of
// BOTH rule halves (cols +0 and +64). Same 8 ds_read_b128 + 16 MFMA per
// k-iter as R3, but the rule-sum lam0*sig(h0)+lam1*sig(h1) happens entirely
// in registers: no ypart LDS round-trip, no atomics (R4: LDS atomicAdd
// collapsed MfmaUtil to 11%), no epilogue barriers.
// - Bias folded into acc init (exact).
// - Lambda staged interleaved lamsh[row*2+rl] (1 KB): one ds_read_b64/(mi,reg).
// - K-chunk XOR swizzle ((row>>1)&3) at the GLOBAL address of global_load_lds
//   (LDS dest stays wave-uniform+lane*16); read applies same XOR. 10M->1.6M.
// - NO min-waves bound (R2: forcing 5 waves/EU spilled acc, WRITE 65->417MB).
__global__ __launch_bounds__(256) void gemm_kernel(const unsigned short* __restrict__ Xb,
                                                   const unsigned short* __restrict__ Wb,
                                                   const float* __restrict__ bias,
                                                   const float* __restrict__ lam,
                                                   unsigned short* __restrict__ partial) {
  __shared__ __align__(16) unsigned char smem[17408];
  unsigned short* Atile = (unsigned short*)smem;           // 128 rows x 32 k (8 KB)
  unsigned short* Btile = (unsigned short*)(smem + 8192);  // 8 KB
  float* lamsh = (float*)(smem + 16384);                   // [128][2] (1 KB)

  const int t = threadIdx.x;
  const int lane = t & 63;
  const int w = t >> 6;
  const int wm = w & 1;        // wave row half (rows wm*64..+63)
  const int oh = w >> 1;       // o-column half (cols oh*32..+31 of each rule)
  const int quad = lane >> 4;  // 0..3
  const int l16 = lane & 15;
  const int gm0 = blockIdx.y * 128;
  const int gn0 = blockIdx.x * 128;

  // stage lambda interleaved: lamsh[row*2+rl] = lam[gm0+row, bx*2+rl]
  {
    int row = t >> 1, rl = t & 1;
    lamsh[t] = lam[(size_t)(gm0 + row) * 64 + blockIdx.x * 2 + rl];
  }

  // acc init = bias (C/D col = l16, same for all 4 regs) — exact fold
  floatx4 acc[4][2][2];
#pragma unroll
  for (int rh = 0; rh < 2; ++rh)
#pragma unroll
    for (int ni = 0; ni < 2; ++ni) {
      float bv = bias[gn0 + rh * 64 + oh * 32 + ni * 16 + l16];
#pragma unroll
      for (int mi = 0; mi < 4; ++mi)
        acc[mi][rh][ni] = (floatx4){bv, bv, bv, bv};
    }

  for (int k0 = 0; k0 < K_DIM; k0 += 32) {
    __syncthreads();
#pragma unroll
    for (int i = 0; i < 2; ++i) {
      int idx = i * 256 + t;       // 0..511, lane-contiguous within each wave
      int row = idx >> 2;          // tile row 0..127
      int cc = idx & 3;            // LDS chunk slot within BK=32
      int gcc = cc ^ ((row >> 1) & 3);  // global k-chunk held in this slot
      const unsigned short* ga = Xb + (size_t)(gm0 + row) * K_DIM + k0 + gcc * 8;
      const unsigned short* gb = Wb + (size_t)(gn0 + row) * K_DIM + k0 + gcc * 8;
      __builtin_amdgcn_global_load_lds(
          (const __attribute__((address_space(1))) void*)ga,
          (__attribute__((address_space(3))) void*)(Atile + idx * 8), 16, 0, 0);
      __builtin_amdgcn_global_load_lds(
          (const __attribute__((address_space(1))) void*)gb,
          (__attribute__((address_space(3))) void*)(Btile + idx * 8), 16, 0, 0);
    }
    __syncthreads();

    bf16x8 af[4], bfr[2][2];
#pragma unroll
    for (int mi = 0; mi < 4; ++mi) {
      int row = wm * 64 + mi * 16 + l16;
      int cc = quad ^ ((row >> 1) & 3);
      af[mi] = *(const bf16x8*)(Atile + row * 32 + cc * 8);
    }
#pragma unroll
    for (int rh = 0; rh < 2; ++rh)
#pragma unroll
      for (int ni = 0; ni < 2; ++ni) {
        int row = rh * 64 + oh * 32 + ni * 16 + l16;
        int cc = quad ^ ((row >> 1) & 3);
        bfr[rh][ni] = *(const bf16x8*)(Btile + row * 32 + cc * 8);
      }
#pragma unroll
    for (int mi = 0; mi < 4; ++mi)
#pragma unroll
      for (int rh = 0; rh < 2; ++rh)
#pragma unroll
        for (int ni = 0; ni < 2; ++ni)
          acc[mi][rh][ni] =
              __builtin_amdgcn_mfma_f32_16x16x32_bf16(af[mi], bfr[rh][ni], acc[mi][rh][ni], 0, 0, 0);
  }

  // ---- epilogue: pure-register rule-sum, no barriers, direct global store ----
  // lamsh was written before the K-loop; the loop's barriers ordered it.
  unsigned short* pbase = partial + (size_t)blockIdx.x * SO + (size_t)gm0 * O_DIM;
#pragma unroll
  for (int mi = 0; mi < 4; ++mi) {
#pragma unroll
    for (int reg = 0; reg < 4; ++reg) {
      int row = wm * 64 + mi * 16 + quad * 4 + reg;
      float2 lv = *(const float2*)(lamsh + row * 2);
#pragma unroll
      for (int ni = 0; ni < 2; ++ni) {
        float h0 = 1.f / (1.f + __expf(-acc[mi][0][ni][reg]));
        float h1 = 1.f / (1.f + __expf(-acc[mi][1][ni][reg]));
        float y = lv.x * h0 + lv.y * h1;
        pbase[(size_t)row * O_DIM + oh * 32 + ni * 16 + l16] = f2bf(y);
      }
    }
  }
}

// ---------------------------------------------------------------- final reduce over 32 N-tiles
__global__ __launch_bounds__(256) void reduce_kernel(const unsigned short* __restrict__ partial,
                                                     float* __restrict__ Y) {
  int i4 = blockIdx.x * 256 + threadIdx.x;  // index of a 4-elem group
  float s0 = 0.f, s1 = 0.f, s2 = 0.f, s3 = 0.f;
#pragma unroll
  for (int c = 0; c < 32; ++c) {
    ushx4 v = ((const ushx4*)(partial + (size_t)c * SO))[i4];
    s0 += bf2f(v.x); s1 += bf2f(v.y); s2 += bf2f(v.z); s3 += bf2f(v.w);
  }
  ((float4*)Y)[i4] = (float4){s0, s1, s2, s3};
}

extern "C" void kernel_launch(void* const* d_in, const int* in_sizes, int n_in,
                              void* d_out, int out_size, void* d_ws, size_t ws_size,
                              hipStream_t stream) {
  const float* X = (const float*)d_in[0];     // [8192,1024]
  const float* W = (const float*)d_in[1];     // [4096,1024]
  const float* b = (const float*)d_in[2];     // [4096]
  const float* lam = (const float*)d_in[3];   // [8192,64]
  float* Y = (float*)d_out;                   // [8192,64]

  unsigned short* Xb = (unsigned short*)d_ws;                       // 16 MB
  unsigned short* Wb = Xb + (size_t)S_DIM * K_DIM;                  // 8 MB
  unsigned short* partial = Wb + (size_t)RO_DIM * K_DIM;            // 32 slices x 1 MB = 32 MB

  int nCast = ((S_DIM + RO_DIM) * K_DIM / 4) / 256;  // 12288 blocks
  cast_kernel<<<nCast, 256, 0, stream>>>(X, W, Xb, Wb);

  dim3 g(RO_DIM / 128, S_DIM / 128);  // (32, 64)
  gemm_kernel<<<g, 256, 0, stream>>>(Xb, Wb, b, lam, partial);

  reduce_kernel<<<SO / 1024, 256, 0, stream>>>(partial, Y);
}

// Round 6
// 186.855 us; speedup vs baseline: 1.7993x; 1.0715x over previous
//
#include <hip/hip_runtime.h>

// Problem constants
#define S_DIM 8192
#define K_DIM 1024
#define RO_DIM 4096
#define O_DIM 64
#define SO (S_DIM * O_DIM)

typedef __attribute__((ext_vector_type(8))) __bf16 bf16x8;
typedef __attribute__((ext_vector_type(4))) float floatx4;
typedef __attribute__((ext_vector_type(4))) unsigned short ushx4;

__device__ inline unsigned short f2bf(float f) {
  unsigned u = __builtin_bit_cast(unsigned, f);
  u += 0x7fff + ((u >> 16) & 1);  // round-to-nearest-even
  return (unsigned short)(u >> 16);
}
__device__ inline float bf2f(unsigned short h) {
  unsigned u = ((unsigned)h) << 16;
  return __builtin_bit_cast(float, u);
}

// ---------------------------------------------------------------- cast X,W -> bf16
// grid-stride x4: each thread handles 4 float4 groups (64B read / 32B write).
__global__ __launch_bounds__(256) void cast_kernel(const float* __restrict__ X,
                                                   const float* __restrict__ W,
                                                   unsigned short* __restrict__ Xb,
                                                   unsigned short* __restrict__ Wb) {
  const int NX4 = (S_DIM * K_DIM) / 4;  // 2,097,152 (multiple of 1024 -> block-uniform branch)
#pragma unroll
  for (int i = 0; i < 4; ++i) {
    int g = blockIdx.x * 1024 + i * 256 + threadIdx.x;
    float4 v;
    unsigned short* dst;
    if (g < NX4) {
      v = ((const float4*)X)[g];
      dst = Xb + (size_t)g * 4;
    } else {
      int j = g - NX4;
      v = ((const float4*)W)[j];
      dst = Wb + (size_t)j * 4;
    }
    ushx4 o;
    o.x = f2bf(v.x); o.y = f2bf(v.y); o.z = f2bf(v.z); o.w = f2bf(v.w);
    *(ushx4*)dst = o;
  }
}

// ---------------------------------------------------------------- fused GEMM+sigmoid+rule-reduce
// 128x128 tile, BK=64 (16 k0-iters vs 32: halves the vmcnt(0)+s_barrier drain
// count per MFMA — the structural ~20% stall of this K-loop shape), 4 waves x
// 16x16x32 MFMA. Wave (wm,oh) = rows wm*64..+63 x cols {oh*32..+31} of BOTH
// rule halves; rule-sum lam0*sig(h0)+lam1*sig(h1) entirely in registers
// (R5: zero LDS bank conflicts, no epilogue barriers).
// - Bias folded into acc init (exact).
// - BK=64 row stride = 128B = full bank wrap -> XOR chunk slot with (row&7):
//   16 consecutive fragment rows cover all 8 chunk positions 2x = free.
//   Swizzle applied at the GLOBAL address of global_load_lds (LDS dest stays
//   wave-uniform + lane*16).
// - NO min-waves bound (R2: forcing 5 waves/EU spilled acc, WRITE 65->417MB).
// - fp8/MX rejected: absmax 0.125 at bf16; e4m3's 32x coarser mantissa would
//   blow the 0.46 threshold.
__global__ __launch_bounds__(256) void gemm_kernel(const unsigned short* __restrict__ Xb,
                                                   const unsigned short* __restrict__ Wb,
                                                   const float* __restrict__ bias,
                                                   const float* __restrict__ lam,
                                                   unsigned short* __restrict__ partial) {
  __shared__ __align__(16) unsigned char smem[33792];
  unsigned short* Atile = (unsigned short*)smem;           // 128 rows x 64 k (16 KB)
  unsigned short* Btile = (unsigned short*)(smem + 16384); // 16 KB
  float* lamsh = (float*)(smem + 32768);                   // [128][2] (1 KB)

  const int t = threadIdx.x;
  const int lane = t & 63;
  const int w = t >> 6;
  const int wm = w & 1;        // wave row half (rows wm*64..+63)
  const int oh = w >> 1;       // o-column half (cols oh*32..+31 of each rule)
  const int quad = lane >> 4;  // 0..3
  const int l16 = lane & 15;
  const int gm0 = blockIdx.y * 128;
  const int gn0 = blockIdx.x * 128;

  // stage lambda interleaved: lamsh[row*2+rl] = lam[gm0+row, bx*2+rl]
  {
    int row = t >> 1, rl = t & 1;
    lamsh[t] = lam[(size_t)(gm0 + row) * 64 + blockIdx.x * 2 + rl];
  }

  // acc init = bias (C/D col = l16, same for all 4 regs) — exact fold
  floatx4 acc[4][2][2];
#pragma unroll
  for (int rh = 0; rh < 2; ++rh)
#pragma unroll
    for (int ni = 0; ni < 2; ++ni) {
      float bv = bias[gn0 + rh * 64 + oh * 32 + ni * 16 + l16];
#pragma unroll
      for (int mi = 0; mi < 4; ++mi)
        acc[mi][rh][ni] = (floatx4){bv, bv, bv, bv};
    }

  for (int k0 = 0; k0 < K_DIM; k0 += 64) {
    __syncthreads();
#pragma unroll
    for (int i = 0; i < 4; ++i) {
      int idx = i * 256 + t;       // 0..1023, lane-contiguous within each wave
      int row = idx >> 3;          // tile row 0..127
      int cc = idx & 7;            // LDS chunk slot within BK=64 (8 x 8 elems)
      int gcc = cc ^ (row & 7);    // global k-chunk held in this slot
      const unsigned short* ga = Xb + (size_t)(gm0 + row) * K_DIM + k0 + gcc * 8;
      const unsigned short* gb = Wb + (size_t)(gn0 + row) * K_DIM + k0 + gcc * 8;
      __builtin_amdgcn_global_load_lds(
          (const __attribute__((address_space(1))) void*)ga,
          (__attribute__((address_space(3))) void*)(Atile + idx * 8), 16, 0, 0);
      __builtin_amdgcn_global_load_lds(
          (const __attribute__((address_space(1))) void*)gb,
          (__attribute__((address_space(3))) void*)(Btile + idx * 8), 16, 0, 0);
    }
    __syncthreads();

    // two k-steps of 32; lane needs k = s*32 + quad*8 -> chunk slot = (s*4+quad) ^ (row&7)
#pragma unroll
    for (int s = 0; s < 2; ++s) {
      bf16x8 af[4], bfr[2][2];
#pragma unroll
      for (int mi = 0; mi < 4; ++mi) {
        int row = wm * 64 + mi * 16 + l16;
        int cc = (s * 4 + quad) ^ (row & 7);
        af[mi] = *(const bf16x8*)(Atile + row * 64 + cc * 8);
      }
#pragma unroll
      for (int rh = 0; rh < 2; ++rh)
#pragma unroll
        for (int ni = 0; ni < 2; ++ni) {
          int row = rh * 64 + oh * 32 + ni * 16 + l16;
          int cc = (s * 4 + quad) ^ (row & 7);
          bfr[rh][ni] = *(const bf16x8*)(Btile + row * 64 + cc * 8);
        }
#pragma unroll
      for (int mi = 0; mi < 4; ++mi)
#pragma unroll
        for (int rh = 0; rh < 2; ++rh)
#pragma unroll
          for (int ni = 0; ni < 2; ++ni)
            acc[mi][rh][ni] =
                __builtin_amdgcn_mfma_f32_16x16x32_bf16(af[mi], bfr[rh][ni], acc[mi][rh][ni], 0, 0, 0);
    }
  }

  // ---- epilogue: pure-register rule-sum, no barriers, direct global store ----
  unsigned short* pbase = partial + (size_t)blockIdx.x * SO + (size_t)gm0 * O_DIM;
#pragma unroll
  for (int mi = 0; mi < 4; ++mi) {
#pragma unroll
    for (int reg = 0; reg < 4; ++reg) {
      int row = wm * 64 + mi * 16 + quad * 4 + reg;
      float2 lv = *(const float2*)(lamsh + row * 2);
#pragma unroll
      for (int ni = 0; ni < 2; ++ni) {
        float h0 = 1.f / (1.f + __expf(-acc[mi][0][ni][reg]));
        float h1 = 1.f / (1.f + __expf(-acc[mi][1][ni][reg]));
        float y = lv.x * h0 + lv.y * h1;
        pbase[(size_t)row * O_DIM + oh * 32 + ni * 16 + l16] = f2bf(y);
      }
    }
  }
}

// ---------------------------------------------------------------- final reduce over 32 N-tiles
__global__ __launch_bounds__(256) void reduce_kernel(const unsigned short* __restrict__ partial,
                                                     float* __restrict__ Y) {
  int i4 = blockIdx.x * 256 + threadIdx.x;  // index of a 4-elem group
  float s0 = 0.f, s1 = 0.f, s2 = 0.f, s3 = 0.f;
#pragma unroll
  for (int c = 0; c < 32; ++c) {
    ushx4 v = ((const ushx4*)(partial + (size_t)c * SO))[i4];
    s0 += bf2f(v.x); s1 += bf2f(v.y); s2 += bf2f(v.z); s3 += bf2f(v.w);
  }
  ((float4*)Y)[i4] = (float4){s0, s1, s2, s3};
}

extern "C" void kernel_launch(void* const* d_in, const int* in_sizes, int n_in,
                              void* d_out, int out_size, void* d_ws, size_t ws_size,
                              hipStream_t stream) {
  const float* X = (const float*)d_in[0];     // [8192,1024]
  const float* W = (const float*)d_in[1];     // [4096,1024]
  const float* b = (const float*)d_in[2];     // [4096]
  const float* lam = (const float*)d_in[3];   // [8192,64]
  float* Y = (float*)d_out;                   // [8192,64]

  unsigned short* Xb = (unsigned short*)d_ws;                       // 16 MB
  unsigned short* Wb = Xb + (size_t)S_DIM * K_DIM;                  // 8 MB
  unsigned short* partial = Wb + (size_t)RO_DIM * K_DIM;            // 32 slices x 1 MB = 32 MB

  int nCast = ((S_DIM + RO_DIM) * K_DIM / 4) / 1024;  // 3072 blocks, 4 float4/thread
  cast_kernel<<<nCast, 256, 0, stream>>>(X, W, Xb, Wb);

  dim3 g(RO_DIM / 128, S_DIM / 128);  // (32, 64)
  gemm_kernel<<<g, 256, 0, stream>>>(Xb, Wb, b, lam, partial);

  reduce_kernel<<<SO / 1024, 256, 0, stream>>>(partial, Y);
}